// Round 8
// baseline (3783.262 us; speedup 1.0000x reference)
//
#include <hip/hip_runtime.h>
#include <cstdint>

#define HDIM   1536
#define DIN    256
#define NSTEP  1008     // (T-1)*B = 63*16
#define NWG    256
#define TPB    512
#define UPW    6        // hidden units per WG per layer (256*6 = 1536)
#define XN     256      // x elements per step
#define NREP   8        // exchange replicas (spread LLC line contention)

// Exchange chunk: u64 = v0 | v1<<16 | v2<<32 | tag<<48  (3 bf16 h values + 16-bit tag)
// A "duplex" = 2 adjacent chunks = 6 values = one WG's per-layer output, 16B aligned.
// Replica r occupies ws64[r*2048 .. r*2048+2047], layout within a replica:
//   [0    .. 1023]  h0 chunks [2 parity][512]
//   [1024 .. 2047]  h1 chunks [2 parity][512]
// u32[32768] = dtype flag (1 = fp32 inputs, 0 = bf16 inputs)
// Producer phase p: h0(p) -> parity p&1, tag p+1 ; h1(p-1) -> parity (p+1)&1, tag p+1.
// Consumer phase n: wants tag n on h0 parity (n+1)&1 and h1 parity n&1.
#define C_H0      0
#define C_H1      1024
#define REP_STRIDE 2048
#define WS_FLAG_W 32768

typedef uint32_t u32x4 __attribute__((ext_vector_type(4)));

__device__ __forceinline__ float bflo(uint32_t p){ union{uint32_t u; float f;} v; v.u = p << 16; return v.f; }
__device__ __forceinline__ float bfhi(uint32_t p){ union{uint32_t u; float f;} v; v.u = p & 0xffff0000u; return v.f; }
__device__ __forceinline__ float bf2f(uint16_t b){ union{uint32_t u; float f;} v; v.u = ((uint32_t)b) << 16; return v.f; }
__device__ __forceinline__ uint16_t f2bf(float f){
    union{float f; uint32_t u;} v; v.f = f;
    uint32_t r = v.u + 0x7fffu + ((v.u >> 16) & 1u);   // RNE
    return (uint16_t)(r >> 16);
}
__device__ __forceinline__ uint32_t packbf(float lo, float hi){
    return (uint32_t)f2bf(lo) | ((uint32_t)f2bf(hi) << 16);
}
// inf-safe fast tanh: 1 - 2/(e^{2x}+1)
__device__ __forceinline__ float tanh_fast(float x){
    return 1.f - 2.f/(__expf(2.f*x) + 1.f);
}

// packed-bf16 2-way dot with fp32 accumulate
#if __has_builtin(__builtin_amdgcn_fdot2_f32_bf16)
typedef __bf16 bf16x2 __attribute__((ext_vector_type(2)));
__device__ __forceinline__ float dot2bf(uint32_t a, uint32_t b, float c){
    return __builtin_amdgcn_fdot2_f32_bf16(__builtin_bit_cast(bf16x2, a),
                                           __builtin_bit_cast(bf16x2, b), c, false);
}
#else
__device__ __forceinline__ float dot2bf(uint32_t a, uint32_t b, float c){
    c = fmaf(bflo(a), bflo(b), c);
    c = fmaf(bfhi(a), bfhi(b), c);
    return c;
}
#endif

// 16B system-coherent load (bypasses L1 + non-coherent XCD L2, reads LLC)
__device__ __forceinline__ u32x4 poll16(const uint64_t* p){
    u32x4 r;
    asm volatile("global_load_dwordx4 %0, %1, off sc0 sc1\n\t"
                 "s_waitcnt vmcnt(0)"
                 : "=v"(r) : "v"(p) : "memory");
    return r;
}

// sum across all 64 lanes, result in every lane
__device__ __forceinline__ float wave_sum(float x){
    #pragma unroll
    for (int o = 1; o < 64; o <<= 1) x += __shfl_xor(x, o, 64);
    return x;
}

// ---------------------------------------------------------------------------
// init kernel: seed boot chunks in all replicas + dtype probe
// ---------------------------------------------------------------------------
__global__ void init_ws(const uint32_t* __restrict__ w, uint32_t* __restrict__ ws){
    uint64_t* ws64 = (uint64_t*)ws;
    const int i = blockIdx.x * blockDim.x + threadIdx.x;   // 0 .. NREP*512-1
    if (i < NREP*512){
        const int rep = i >> 9, j = i & 511;
        uint64_t* base = ws64 + rep*REP_STRIDE;
        base[C_H0 + 512 + j] = 0ull;                  // h0(-1): parity 1, tag 0, zeros
        base[C_H1 + j]       = 0ull;                  // h1(-2): parity 0, tag 0, zeros
        base[C_H1 + 512 + j] = ((uint64_t)1 << 48);   // h1(-1): parity 1, tag 1, zeros
    }
    if (blockIdx.x == 0 && threadIdx.x < 64){
        const int t = threadIdx.x;
        int cnt = 0;
        #pragma unroll
        for (int j = 0; j < 4; ++j){
            const uint32_t v = w[t*4 + j];
            const uint32_t e = (v >> 7) & 0xFFu;
            if (e == 0u || (e >= 0x70u && e <= 0x7Cu)) cnt++;
        }
        #pragma unroll
        for (int o = 1; o < 64; o <<= 1) cnt += __shfl_xor(cnt, o, 64);
        if (t == 0)
            ws[WS_FLAG_W] = (cnt < 128) ? 1u : 0u;   // sparse in-window => fp32
    }
}

__global__ __launch_bounds__(TPB, 2)
void lstm_seq_kernel(const void* __restrict__ batch_,
                     const void* __restrict__ Wih0_,
                     const void* __restrict__ Whh0_,
                     const void* __restrict__ bih0_,
                     const void* __restrict__ bhh0_,
                     const void* __restrict__ Wih1_,
                     const void* __restrict__ Whh1_,
                     const void* __restrict__ bih1_,
                     const void* __restrict__ bhh1_,
                     void* __restrict__ out_,
                     uint32_t* __restrict__ ws)
{
    __shared__ uint32_t lds_w[8*3*8*64];   // L1 rows, h0-chunks 0..7 (packed bf16)
    __shared__ uint32_t lds_h[1536];       // packed h pairs: [0..767]=h0, [768..1535]=h1
    __shared__ float    lds_pre[48];       // 24 L0 + 24 L1 pre-activations
    __shared__ float    lds_b[48];         // fused biases
    __shared__ float    lds_c[12];         // c-state (0-5: L0 by wave0; 6-11: L1 by wave1)
    __shared__ float    lds_hout[12];      // h-state (fp32), same ownership

    const int g   = blockIdx.x;
    const int tid = threadIdx.x;
    const int w   = tid >> 6;
    const int l   = tid & 63;

    const uint32_t fp32in = __hip_atomic_load(&ws[WS_FLAG_W],
                             __ATOMIC_RELAXED, __HIP_MEMORY_SCOPE_AGENT);
    uint64_t* ws64 = (uint64_t*)ws;

    // ---------------- init ----------------
    if (tid < 24){
        const int uu = tid >> 2, gate = tid & 3;
        const int grow = gate*HDIM + g*UPW + uu;
        if (fp32in){
            lds_b[tid]      = ((const float*)bih0_)[grow] + ((const float*)bhh0_)[grow];
            lds_b[24 + tid] = ((const float*)bih1_)[grow] + ((const float*)bhh1_)[grow];
        } else {
            lds_b[tid]      = bf2f(((const uint16_t*)bih0_)[grow]) + bf2f(((const uint16_t*)bhh0_)[grow]);
            lds_b[24 + tid] = bf2f(((const uint16_t*)bih1_)[grow]) + bf2f(((const uint16_t*)bhh1_)[grow]);
        }
    }
    if (tid < 12){ lds_c[tid] = 0.f; lds_hout[tid] = 0.f; }

    // ---------------- persistent weight load (once) ----------------
    uint32_t w0[3][14];    // L0: 2 x-chunks (W_ih0) + 12 h-chunks (W_hh0), packed bf16
    uint32_t w1r[3][16];   // L1: chunks 8..11 (W_ih1) + 12..23 (W_hh1)

    if (fp32in){
        const float2* Wih0f = (const float2*)Wih0_;
        const float2* Whh0f = (const float2*)Whh0_;
        const float2* Wih1f = (const float2*)Wih1_;
        const float2* Whh1f = (const float2*)Whh1_;
        #pragma unroll
        for (int j = 0; j < 3; ++j){
            const int rr = w*3 + j;
            const int grow = (rr & 3)*HDIM + g*UPW + (rr >> 2);
            float2 t;
            t = Wih0f[grow*(DIN/2) + l];        w0[j][0] = packbf(t.x, t.y);
            t = Wih0f[grow*(DIN/2) + 64 + l];   w0[j][1] = packbf(t.x, t.y);
            #pragma unroll
            for (int c = 2; c < 14; ++c){
                t = Whh0f[grow*(HDIM/2) + (c-2)*64 + l]; w0[j][c] = packbf(t.x, t.y);
            }
            #pragma unroll
            for (int c = 0; c < 8; ++c){
                t = Wih1f[grow*(HDIM/2) + c*64 + l];
                lds_w[((w*3 + j)*8 + c)*64 + l] = packbf(t.x, t.y);
            }
            #pragma unroll
            for (int c = 8; c < 12; ++c){
                t = Wih1f[grow*(HDIM/2) + c*64 + l]; w1r[j][c-8] = packbf(t.x, t.y);
            }
            #pragma unroll
            for (int c = 12; c < 24; ++c){
                t = Whh1f[grow*(HDIM/2) + (c-12)*64 + l]; w1r[j][c-8] = packbf(t.x, t.y);
            }
        }
    } else {
        const uint32_t* Wih0p = (const uint32_t*)Wih0_;
        const uint32_t* Whh0p = (const uint32_t*)Whh0_;
        const uint32_t* Wih1p = (const uint32_t*)Wih1_;
        const uint32_t* Whh1p = (const uint32_t*)Whh1_;
        #pragma unroll
        for (int j = 0; j < 3; ++j){
            const int rr = w*3 + j;
            const int grow = (rr & 3)*HDIM + g*UPW + (rr >> 2);
            w0[j][0] = Wih0p[grow*(DIN/2) + l];
            w0[j][1] = Wih0p[grow*(DIN/2) + 64 + l];
            #pragma unroll
            for (int c = 2; c < 14; ++c)
                w0[j][c] = Whh0p[grow*(HDIM/2) + (c-2)*64 + l];
            #pragma unroll
            for (int c = 0; c < 8; ++c)
                lds_w[((w*3 + j)*8 + c)*64 + l] = Wih1p[grow*(HDIM/2) + c*64 + l];
            #pragma unroll
            for (int c = 8; c < 12; ++c)
                w1r[j][c-8] = Wih1p[grow*(HDIM/2) + c*64 + l];
            #pragma unroll
            for (int c = 12; c < 24; ++c)
                w1r[j][c-8] = Whh1p[grow*(HDIM/2) + (c-12)*64 + l];
        }
    }
    // lds_w consumed only after the first phase's __syncthreads.

    // poll address components (constant across phases except parity)
    const int players = tid >> 8;          // 0 = h0, 1 = h1
    const int pidx    = tid & 255;         // duplex index (producer WG id)
    uint64_t* myrep   = ws64 + (g & (NREP-1))*REP_STRIDE;   // this WG's poll replica

    // ---------------- sequential phases ----------------
    // phase n computes layer0(t=n) [n<NSTEP] and layer1(t=n-1) [n>=1]
    for (int n = 0; n <= NSTEP; ++n){
        // x load issued first so it's in flight during the spin
        uint32_t xp0, xp1;
        {
            const int nn = (n < NSTEP) ? n : 0;
            const int xbase = ((nn & 15)*64 + (nn >> 4) + 1) * XN;  // batch[b][ei]
            if (fp32in){
                const float2* bp = (const float2*)((const float*)batch_ + xbase);
                const float2 t0 = bp[l];
                const float2 t1 = bp[64 + l];
                xp0 = packbf(t0.x, t0.y); xp1 = packbf(t1.x, t1.y);
            } else {
                const uint32_t* bp = (const uint32_t*)batch_ + (xbase >> 1);
                xp0 = bp[l]; xp1 = bp[64 + l];
            }
        }

        // one 16B poll per thread: a duplex = 2 self-tagged chunks = 6 h values.
        // h0 polls (threads 0..255) gate the recurrence; h1 polls have >=1
        // phase of slack (h1 published mid-previous-phase) and rarely spin.
        u32x4 r;
        {
            const uint64_t* ap = myrep
                + (players ? (C_H1 + (n & 1)*512) : (C_H0 + ((n+1) & 1)*512))
                + 2*pidx;
            const uint32_t want = (uint32_t)n & 0xFFFFu;
            r = poll16(ap);
            while ((r.y >> 16) != want || (r.w >> 16) != want){
                __builtin_amdgcn_s_sleep(1);
                r = poll16(ap);
            }
        }
        {
            const int base = players*768 + 3*pidx;
            lds_h[base]     = r.x;                                   // v0|v1
            lds_h[base + 1] = (r.y & 0xFFFFu) | (r.z << 16);         // v2|v3
            lds_h[base + 2] = (r.z >> 16)     | (r.w << 16);         // v4|v5
        }
        __syncthreads();   // sync1: lds_h ready

        // per-lane packed h0 pairs (h1 deferred — off critical path)
        uint32_t h0p[12];
        #pragma unroll
        for (int k = 0; k < 12; ++k) h0p[k] = lds_h[k*64 + l];

        // ---- L0 dots (critical path) ----
        float acc0[3];
        #pragma unroll
        for (int j = 0; j < 3; ++j){
            float a = dot2bf(w0[j][0], xp0, 0.f);
            a = dot2bf(w0[j][1], xp1, a);
            #pragma unroll
            for (int k = 0; k < 12; ++k)
                a = dot2bf(w0[j][k+2], h0p[k], a);
            acc0[j] = a;
        }
        #pragma unroll
        for (int j = 0; j < 3; ++j){
            const float r0 = wave_sum(acc0[j]);
            if (l == 0) lds_pre[w*3 + j] = r0;
        }
        __syncthreads();   // sync2: L0 pre-activations ready

        // ---- wave 0: L0 cell + IMMEDIATE h0 publish (critical path) ----
        if (w == 0){
            float hpub = 0.f;
            if (l < 6 && n < NSTEP){
                const float* pre = &lds_pre[l*4];
                const float* bb  = &lds_b[l*4];
                const float gi = pre[0] + bb[0];
                const float gf = pre[1] + bb[1];
                const float gg = pre[2] + bb[2];
                const float go = pre[3] + bb[3];
                const float si = 1.f/(1.f + __expf(-gi));
                const float sf = 1.f/(1.f + __expf(-gf));
                const float so = 1.f/(1.f + __expf(-go));
                const float cn = sf*lds_c[l] + si*tanh_fast(gg);
                const float hn = so * tanh_fast(cn);
                lds_c[l] = cn;
                lds_hout[l] = hn;
                hpub = hn;
            }
            // lanes 0..15: replica = l>>1, duplex slot = l&1 (all lanes run shfl)
            const int slot = l & 1;
            const float s0 = __shfl(hpub, 3*slot,     64);
            const float s1 = __shfl(hpub, 3*slot + 1, 64);
            const float s2 = __shfl(hpub, 3*slot + 2, 64);
            if (l < 2*NREP && n < NSTEP){
                const uint64_t tag = (uint64_t)((uint32_t)(n + 1) & 0xFFFFu);
                const uint64_t pk = (uint64_t)f2bf(s0)
                                  | ((uint64_t)f2bf(s1) << 16)
                                  | ((uint64_t)f2bf(s2) << 32)
                                  | (tag << 48);
                uint64_t* dst = ws64 + (l >> 1)*REP_STRIDE
                              + C_H0 + (n & 1)*512 + 2*g + slot;
                __hip_atomic_store(dst, pk, __ATOMIC_RELAXED, __HIP_MEMORY_SCOPE_AGENT);
            }
        }

        // ---- L1 dots (shadow of the h0 exchange) ----
        uint32_t h1p[12];
        #pragma unroll
        for (int k = 0; k < 12; ++k) h1p[k] = lds_h[768 + k*64 + l];

        float acc1[3];
        #pragma unroll
        for (int j = 0; j < 3; ++j){
            float a = 0.f;
            #pragma unroll
            for (int k = 0; k < 8; ++k)
                a = dot2bf(lds_w[((w*3 + j)*8 + k)*64 + l], h0p[k], a);
            #pragma unroll
            for (int k = 8; k < 12; ++k)
                a = dot2bf(w1r[j][k-8], h0p[k], a);
            #pragma unroll
            for (int k = 0; k < 12; ++k)
                a = dot2bf(w1r[j][k+4], h1p[k], a);
            acc1[j] = a;
        }
        #pragma unroll
        for (int j = 0; j < 3; ++j){
            const float r1 = wave_sum(acc1[j]);
            if (l == 0) lds_pre[24 + w*3 + j] = r1;
        }
        __syncthreads();   // sync3: L1 pre-activations ready

        // ---- wave 1: L1 cell + h1 publish (has >=1 phase of slack) ----
        if (w == 1){
            float hpub = 0.f;
            if (l < 6 && n >= 1){
                const float* pre = &lds_pre[24 + l*4];
                const float* bb  = &lds_b[24 + l*4];
                const float gi = pre[0] + bb[0];
                const float gf = pre[1] + bb[1];
                const float gg = pre[2] + bb[2];
                const float go = pre[3] + bb[3];
                const float si = 1.f/(1.f + __expf(-gi));
                const float sf = 1.f/(1.f + __expf(-gf));
                const float so = 1.f/(1.f + __expf(-go));
                const float cn = sf*lds_c[6 + l] + si*tanh_fast(gg);
                const float hn = so * tanh_fast(cn);
                lds_c[6 + l] = cn;
                lds_hout[6 + l] = hn;
                hpub = hn;
            }
            const int slot = l & 1;
            const float s0 = __shfl(hpub, 3*slot,     64);
            const float s1 = __shfl(hpub, 3*slot + 1, 64);
            const float s2 = __shfl(hpub, 3*slot + 2, 64);
            if (l < 2*NREP && n >= 1 && n < NSTEP){
                const uint64_t tag = (uint64_t)((uint32_t)(n + 1) & 0xFFFFu);
                const uint64_t pk = (uint64_t)f2bf(s0)
                                  | ((uint64_t)f2bf(s1) << 16)
                                  | ((uint64_t)f2bf(s2) << 32)
                                  | (tag << 48);
                uint64_t* dst = ws64 + (l >> 1)*REP_STRIDE
                              + C_H1 + ((n+1) & 1)*512 + 2*g + slot;
                __hip_atomic_store(dst, pk, __ATOMIC_RELAXED, __HIP_MEMORY_SCOPE_AGENT);
            }
        }
        // no trailing barrier: next phase's tag spin provides the sync
    }

    // ---------------- output: h[2][1536] ++ c[2][1536] ----------------
    __syncthreads();   // lds_hout[6..11]/lds_c[6..11] written by wave 1
    if (tid < 12){
        const int layer = tid / 6, uu = tid % 6;
        const int oi = layer*HDIM + g*UPW + uu;
        if (fp32in){
            ((float*)out_)[oi]        = lds_hout[tid];
            ((float*)out_)[3072 + oi] = lds_c[tid];
        } else {
            ((uint16_t*)out_)[oi]        = f2bf(lds_hout[tid]);
            ((uint16_t*)out_)[3072 + oi] = f2bf(lds_c[tid]);
        }
    }
}

extern "C" void kernel_launch(void* const* d_in, const int* in_sizes, int n_in,
                              void* d_out, int out_size, void* d_ws, size_t ws_size,
                              hipStream_t stream)
{
    (void)in_sizes; (void)n_in; (void)out_size; (void)ws_size;
    const void* batch = d_in[0];
    const void* Wih0  = d_in[1];
    const void* Whh0  = d_in[2];
    const void* bih0  = d_in[3];
    const void* bhh0  = d_in[4];
    const void* Wih1  = d_in[5];
    const void* Whh1  = d_in[6];
    const void* bih1  = d_in[7];
    const void* bhh1  = d_in[8];
    void* out = d_out;
    uint32_t* ws = (uint32_t*)d_ws;

    hipLaunchKernelGGL(init_ws, dim3((NREP*512 + 255)/256), dim3(256), 0, stream,
                       (const uint32_t*)Whh0, ws);

    void* args[] = { &batch, &Wih0, &Whh0, &bih0, &bhh0,
                     &Wih1, &Whh1, &bih1, &bhh1, &out, &ws };
    hipLaunchCooperativeKernel((const void*)lstm_seq_kernel,
                               dim3(NWG), dim3(TPB), args, 0, stream);
}